// Round 3
// baseline (264.320 us; speedup 1.0000x reference)
//
#include <hip/hip_runtime.h>

// PositionalEncodingAngle: out[n, j] = sin/cos( |clip(x_n,±45)| / 45^(2*floor(e/2)/1024) )
// where e = j if x_n >= 0 else 1023-j; sin for even j, cos for odd j.
// Pair k = j/2 uses inv-denom exp2(-c*k) (x>=0) or exp2(-c*(511-k)) (x<0), c = log2(45)/512.
// Memory-bound: 268 MB f32 write-once output; 40.3 us floor at the 6.66 TB/s measured fill rate.
// Budget: dur_us ~= 201 us harness fills (fixed) + kernel. R6 kernel ~= 52 us (5.2 TB/s).
//
// R6 -> R8: output is written once and never re-read -> non-temporal stores
// (global_store_dwordx4 nt) skip L2 allocation and stream straight to HBM,
// removing the allocate/evict writeback churn of pushing 268 MB through the
// 4 MiB/XCD L2. Target: match the fill kernel's ~6.6 TB/s.
// R8 fix: __builtin_nontemporal_store rejects HIP_vector_type float4* —
// use a native clang ext_vector_type(4) float vector (same 16B layout).

#define PE_D 1024
#define PE_RES 45.0f
#define ROWS_PER_BLOCK 32

typedef float f32x4 __attribute__((ext_vector_type(4)));

__global__ __launch_bounds__(256) void PositionalEncodingAngle_kernel(
    const float* __restrict__ x, float* __restrict__ out) {
    const int tid = threadIdx.x;                 // 0..255 -> j = 4*tid..4*tid+3 (pairs 2*tid, 2*tid+1)
    const int n0  = blockIdx.x * ROWS_PER_BLOCK;

    // c = log2(45)/512
    const float c = 0.010726275578769f;
    const int   k0 = 2 * tid;

    // Loop-invariant inverse denominators for both sign branches.
    const float e_pos0 = exp2f(-c * (float)(k0));
    const float e_pos1 = exp2f(-c * (float)(k0 + 1));
    const float e_neg0 = exp2f(-c * (float)(511 - k0));
    const float e_neg1 = exp2f(-c * (float)(510 - k0));

    // Preload the block's 32 positions (wave-uniform scalar loads, L2-hit).
    float xv[ROWS_PER_BLOCK];
#pragma unroll
    for (int r = 0; r < ROWS_PER_BLOCK; ++r) xv[r] = x[n0 + r];

    f32x4* outv = reinterpret_cast<f32x4*>(out);

#pragma unroll
    for (int r = 0; r < ROWS_PER_BLOCK; r += 4) {
        f32x4 o[4];
#pragma unroll
        for (int i = 0; i < 4; ++i) {
            const float xc = fminf(fmaxf(xv[r + i], -PE_RES), PE_RES);
            const float a  = fabsf(xc);
            const bool  p  = (xc >= 0.0f);
            const float a0 = a * (p ? e_pos0 : e_neg0);
            const float a1 = a * (p ? e_pos1 : e_neg1);
            o[i].x = __sinf(a0); o[i].y = __cosf(a0);
            o[i].z = __sinf(a1); o[i].w = __cosf(a1);
        }
#pragma unroll
        for (int i = 0; i < 4; ++i)
            __builtin_nontemporal_store(o[i], &outv[(size_t)(n0 + r + i) * (PE_D / 4) + tid]);
    }
}

extern "C" void kernel_launch(void* const* d_in, const int* in_sizes, int n_in,
                              void* d_out, int out_size, void* d_ws, size_t ws_size,
                              hipStream_t stream) {
    const float* x = (const float*)d_in[0];
    float* out = (float*)d_out;
    const int N = out_size / PE_D;               // nbatch * nsources = 65536 (multiple of 32)
    const int grid = N / ROWS_PER_BLOCK;         // 2048 blocks = 8/CU
    PositionalEncodingAngle_kernel<<<grid, 256, 0, stream>>>(x, out);
}